// Round 15
// baseline (77.262 us; speedup 1.0000x reference)
//
#include <hip/hip_runtime.h>
#include <math.h>

#define NPTS 4096
#define CDIM 512
#define NROWS 16384
#define NTILES 528   // 32*33/2 tri-tiles of 128 per batch
#define FLTMAX 3.402823466e+38f

typedef _Float16 half_t;
typedef _Float16 half8 __attribute__((ext_vector_type(8)));
typedef float f32x4 __attribute__((ext_vector_type(4)));

__device__ inline void gl_lds16(const void* g, void* l) {
    __builtin_amdgcn_global_load_lds(
        (const __attribute__((address_space(1))) uint32_t*)g,
        (__attribute__((address_space(3))) uint32_t*)l, 16, 0, 0);
}

// Super-tile order: per batch, 4x4 super-grid of 8x8 tiles (upper triangle,
// 10 supers). Decode t in [0,528) -> (I,J), J>=I. Keeps each XCD's resident
// tiles L2-compact (verified R10: FETCH 29->18 MB).
__device__ __forceinline__ void super_decode(int t, int& I, int& J) {
    const int cum[10] = {0, 36, 100, 164, 228, 264, 328, 392, 428, 492};
    const int si[10]  = {0, 0, 0, 0, 1, 1, 1, 2, 2, 3};
    const int sj[10]  = {0, 1, 2, 3, 1, 2, 3, 2, 3, 3};
    int s = 0;
    #pragma unroll
    for (int k = 1; k < 10; ++k) s += (t >= cum[k]);
    const int u = t - cum[s];
    int i, j;
    if (si[s] == sj[s]) {
        i = 0;
        #pragma unroll
        for (int k = 1; k < 8; ++k) {
            const int c8 = k * 8 - (k * (k - 1)) / 2;
            i += (u >= c8);
        }
        const int c8i = i * 8 - (i * (i - 1)) / 2;
        j = i + (u - c8i);
    } else {
        i = u >> 3;
        j = u & 7;
    }
    I = si[s] * 8 + i;
    J = sj[s] * 8 + j;
}

// merge two sorted triples + maxes: (n0<=n1<=n2, nx)
#define TRIMERGE(n0, n1, n2, nx, x0, x1, x2, xx, y0, y1, y2, yx) do {          \
        n0 = fminf(x0, y0);                                                    \
        n1 = fminf(fmaxf(x0, y0), fminf(x1, y1));                              \
        n2 = fminf(fminf(x2, y2), fminf(fmaxf(x0, y1), fmaxf(x1, y0)));        \
        nx = fmaxf(xx, yx);                                                    \
    } while (0)

// ============================================================================
// Path A: prep -> fcm_sym (128x128 tri tiles, super-tile XCD-chunked order,
// BK=32 ring-4 LDS with counted vmcnt, tree-merge epilogue) -> combine
// Global f16 image: row stride 1024 B; 8 Kblocks of 64 ch (128 B); 16B slot s
// of each Kblock stored at position s^(row&7) (pre-baked LDS swizzle).
// ============================================================================

__global__ __launch_bounds__(256) void prep_kernel(const float* __restrict__ x,
                                                   half_t* __restrict__ hi,
                                                   float* __restrict__ sq) {
    const int wv = threadIdx.x >> 6, l = threadIdx.x & 63;
    const int row = blockIdx.x * 4 + wv;
    const float* f = x + (size_t)row * CDIM;
    float4 v0 = *(const float4*)(f + l * 8);
    float4 v1 = *(const float4*)(f + l * 8 + 4);
    float xs[8] = {v0.x, v0.y, v0.z, v0.w, v1.x, v1.y, v1.z, v1.w};
    half8 h;
    float s = 0.0f;
    #pragma unroll
    for (int i = 0; i < 8; ++i) {
        float v = xs[i];
        s = fmaf(v, v, s);
        h[i] = (half_t)v;
    }
    #pragma unroll
    for (int o = 32; o > 0; o >>= 1) s += __shfl_xor(s, o);
    const int kb = l >> 3;
    const int pos = (l & 7) ^ (row & 7);
    *(half8*)(hi + (size_t)row * CDIM + kb * 64 + pos * 8) = h;
    if (l == 0) sq[row] = s;
}

// One block per triangular tile (I,J), J>=I, per batch (super-tile XCD-chunked
// order). 128x128 tile, 4 waves (2x2, 64x64 each), BK=32, 16 K-steps.
// LDS: 4-slot ring, 16 KB each (64 KB -> 2 blocks/CU). Slot layout (R12,
// numerically validated): 128 rows x 128 B; row r position p (16B units)
// holds matrix (p^(r&7))>>2 (0=A,1=B), rel ch-slot (p^(r&7))&3 -> row stride
// 128 B + 8-slot XOR = the measured-0-conflict read pattern.
// Schedule (R6, validated): depth-2 prefetch; per step issue STAGE(t+2),
// then s_waitcnt vmcnt(4) at the step end guarantees slot t+1 complete
// (oldest-4-retired); vmcnt(0) only at the final peel. sq loads are hoisted
// BEFORE STAGE(0) so they are oldest in the vmcnt queue (counting sound).
// Epilogue (R13, validated): tree merges with result distribution.
// Row-side -> slot 2J+wn; col-side (skip if I==J) -> slot 2I+wm.
// part layout: [slot][row] float4 (m0,m1,m2,max), d^2 domain.
__global__ __launch_bounds__(256, 2) void fcm_sym(const half_t* __restrict__ hi,
                                                  const float* __restrict__ sq,
                                                  float4* __restrict__ part4) {
    __shared__ __align__(16) char smem[4][16384];
    const int tid = threadIdx.x, wv = tid >> 6, l = tid & 63;
    const int wm = wv >> 1, wn = wv & 1;
    const int wg = blockIdx.x;
    const int tl = (wg & 7) * 264 + (wg >> 3);        // XCD-chunked, bijective
    const int batch = tl / NTILES;
    const int t = tl - batch * NTILES;
    int I, J;
    super_decode(t, I, J);
    const int r0 = (batch << 12) + I * 128;
    const int c0 = (batch << 12) + J * 128;
    const char* base = (const char*)hi;

    // sq values hoisted before any staging (oldest in vmcnt queue)
    float sr[16];
    #pragma unroll
    for (int mi = 0; mi < 4; ++mi)
        *(float4*)&sr[mi * 4] =
            *(const float4*)&sq[r0 + wm * 64 + mi * 16 + (l >> 4) * 4];
    float scn[4];
    #pragma unroll
    for (int ni = 0; ni < 4; ++ni)
        scn[ni] = sq[c0 + wn * 64 + ni * 16 + (l & 15)];

    // ---- staging algebra (R12-validated, per-thread constants) ----
    const int pos = tid & 7;
    const int r7s = (tid >> 3) & 7;
    const int xs_ = pos ^ r7s;
    const int mS = xs_ >> 2;                           // 0=A(rows of I), 1=B(rows of J)
    const int off0 = (((pos & 3) ^ (r7s & 4)) << 4);
    const int rbase = mS ? c0 : r0;
    size_t offE[4];
    #pragma unroll
    for (int i = 0; i < 4; ++i)
        offE[i] = (size_t)(rbase + i * 32 + (tid >> 3)) * 1024 + off0;

    // ---- fragment read offsets (R12-validated, 0-conflict) ----
    int aoff[4], boff[4];
    #pragma unroll
    for (int q = 0; q < 4; ++q) {
        int ra = wm * 64 + q * 16 + (l & 15);
        aoff[q] = ra * 128 + ((((l >> 4)) ^ (ra & 7)) << 4);
        int rb = wn * 64 + q * 16 + (l & 15);
        boff[q] = rb * 128 + ((((l >> 4) | 4) ^ (rb & 7)) << 4);
    }

#define STAGE(t_) do {                                                        \
        const int rg_ = (t_) & 3;                                             \
        const int kb_ = (t_) >> 1;                                            \
        const size_t hx_ = (size_t)(((t_) & 1) << 6);                         \
        _Pragma("unroll")                                                     \
        for (int i_ = 0; i_ < 4; ++i_)                                        \
            gl_lds16(base + ((offE[i_] ^ hx_) + kb_ * 128),                   \
                     &smem[rg_][i_ * 4096 + tid * 16]);                       \
    } while (0)

    f32x4 acc[4][4];
    #pragma unroll
    for (int mi = 0; mi < 4; ++mi)
        #pragma unroll
        for (int ni = 0; ni < 4; ++ni)
            #pragma unroll
            for (int j = 0; j < 4; ++j) acc[mi][ni][j] = 0.0f;

    // prologue: slots 0 and 1 in flight; wait for slot 0 only
    STAGE(0);
    STAGE(1);
    asm volatile("s_waitcnt vmcnt(4)" ::: "memory");
    __builtin_amdgcn_s_barrier();

    #pragma unroll
    for (int ks = 0; ks < 16; ++ks) {
        const int rg = ks & 3;
        if (ks < 14) STAGE(ks + 2);
        half8 af[4], bf[4];
        #pragma unroll
        for (int q = 0; q < 4; ++q) {
            af[q] = *(const half8*)&smem[rg][aoff[q]];
            bf[q] = *(const half8*)&smem[rg][boff[q]];
        }
        #pragma unroll
        for (int mi = 0; mi < 4; ++mi)
            #pragma unroll
            for (int ni = 0; ni < 4; ++ni)
                acc[mi][ni] = __builtin_amdgcn_mfma_f32_16x16x32_f16(
                    af[mi], bf[ni], acc[mi][ni], 0, 0, 0);
        if (ks < 15) {
            if (ks < 14) asm volatile("s_waitcnt vmcnt(4)" ::: "memory");
            else         asm volatile("s_waitcnt vmcnt(0)" ::: "memory");
            __builtin_amdgcn_s_barrier();
        }
    }
#undef STAGE

    // ---- row-side fold: rows of block I over this tile's 128 cols ----
    float st0[16], st1[16], st2[16], stx[16];
    #pragma unroll
    for (int i = 0; i < 16; ++i) {
        st0[i] = FLTMAX; st1[i] = FLTMAX; st2[i] = FLTMAX; stx[i] = 0.0f;
    }
    #pragma unroll
    for (int ni = 0; ni < 4; ++ni) {
        float sc = scn[ni];
        #pragma unroll
        for (int mi = 0; mi < 4; ++mi)
            #pragma unroll
            for (int j = 0; j < 4; ++j) {
                int idx = mi * 4 + j;
                float d2v = fmaf(-2.0f, acc[mi][ni][j], sr[idx] + sc);
                float lo0 = fminf(st0[idx], d2v), hi0 = fmaxf(st0[idx], d2v);
                st0[idx] = lo0;
                float lo1 = fminf(st1[idx], hi0), hi1 = fmaxf(st1[idx], hi0);
                st1[idx] = lo1;
                st2[idx] = fminf(st2[idx], hi1);
                stx[idx] = fmaxf(stx[idx], d2v);
            }
    }
    // ---- row-side tree-merge: 4 rounds, states 16->8->4->2->1, in place ----
    {
        const int t16 = l & 15;
        #pragma unroll
        for (int rnd = 0; rnd < 4; ++rnd) {
            const int span = 1 << rnd;                 // xor distance
            const int cnt = 8 >> rnd;                  // slots this round
            const bool bit = (t16 & span) != 0;
            #pragma unroll
            for (int q = 0; q < 8; ++q) {
                if (q >= cnt) break;
                float A0 = st0[2 * q],     A1 = st1[2 * q];
                float A2 = st2[2 * q],     AX = stx[2 * q];
                float B0 = st0[2 * q + 1], B1 = st1[2 * q + 1];
                float B2 = st2[2 * q + 1], BX = stx[2 * q + 1];
                float m0v = bit ? B0 : A0, m1v = bit ? B1 : A1;
                float m2v = bit ? B2 : A2, mxv = bit ? BX : AX;
                float o0 = bit ? A0 : B0, o1 = bit ? A1 : B1;
                float o2 = bit ? A2 : B2, ox = bit ? AX : BX;
                float p0 = __shfl_xor(o0, span);
                float p1 = __shfl_xor(o1, span);
                float p2 = __shfl_xor(o2, span);
                float px = __shfl_xor(ox, span);
                TRIMERGE(st0[q], st1[q], st2[q], stx[q],
                         m0v, m1v, m2v, mxv, p0, p1, p2, px);
            }
        }
        // lane t16 now holds merged state i = t16 (mi = t16>>2, j = t16&3)
        const int row = r0 + wm * 64 + (t16 >> 2) * 16 + (l >> 4) * 4 + (t16 & 3);
        part4[(size_t)(2 * J + wn) * NROWS + row] =
            make_float4(st0[0], st1[0], st2[0], stx[0]);
    }

    // ---- col-side fold: rows of block J over this tile's 128 rows ----
    if (J > I) {
        float c0s[4], c1s[4], c2s[4], cxs[4];
        #pragma unroll
        for (int ni = 0; ni < 4; ++ni) {
            c0s[ni] = FLTMAX; c1s[ni] = FLTMAX; c2s[ni] = FLTMAX; cxs[ni] = 0.0f;
        }
        #pragma unroll
        for (int ni = 0; ni < 4; ++ni) {
            float sc = scn[ni];
            #pragma unroll
            for (int mi = 0; mi < 4; ++mi)
                #pragma unroll
                for (int j = 0; j < 4; ++j) {
                    float d2v = fmaf(-2.0f, acc[mi][ni][j], sr[mi * 4 + j] + sc);
                    float lo0 = fminf(c0s[ni], d2v), hi0 = fmaxf(c0s[ni], d2v);
                    c0s[ni] = lo0;
                    float lo1 = fminf(c1s[ni], hi0), hi1 = fmaxf(c1s[ni], hi0);
                    c1s[ni] = lo1;
                    c2s[ni] = fminf(c2s[ni], hi1);
                    cxs[ni] = fmaxf(cxs[ni], d2v);
                }
        }
        // col-side tree-merge: 2 rounds over lane-groups (xor 16, 32)
        {
            #pragma unroll
            for (int rnd = 0; rnd < 2; ++rnd) {
                const int span = 16 << rnd;
                const int cnt = 2 >> rnd;
                const bool bit = (l & span) != 0;
                #pragma unroll
                for (int q = 0; q < 2; ++q) {
                    if (q >= cnt) break;
                    float A0 = c0s[2 * q],     A1 = c1s[2 * q];
                    float A2 = c2s[2 * q],     AX = cxs[2 * q];
                    float B0 = c0s[2 * q + 1], B1 = c1s[2 * q + 1];
                    float B2 = c2s[2 * q + 1], BX = cxs[2 * q + 1];
                    float m0v = bit ? B0 : A0, m1v = bit ? B1 : A1;
                    float m2v = bit ? B2 : A2, mxv = bit ? BX : AX;
                    float o0 = bit ? A0 : B0, o1 = bit ? A1 : B1;
                    float o2 = bit ? A2 : B2, ox = bit ? AX : BX;
                    float p0 = __shfl_xor(o0, span);
                    float p1 = __shfl_xor(o1, span);
                    float p2 = __shfl_xor(o2, span);
                    float px = __shfl_xor(ox, span);
                    TRIMERGE(c0s[q], c1s[q], c2s[q], cxs[q],
                             m0v, m1v, m2v, mxv, p0, p1, p2, px);
                }
            }
            // lane group g = l>>4 holds merged state ni = g
            const int colr = c0 + wn * 64 + ((l >> 4) & 3) * 16 + (l & 15);
            part4[(size_t)(2 * I + wm) * NROWS + colr] =
                make_float4(c0s[0], c1s[0], c2s[0], cxs[0]);
        }
    }
}

// combine: fold all 64 slots per row (each written exactly once), sqrt + pred.
__global__ __launch_bounds__(256) void combine_kernel(const float4* __restrict__ part4,
                                                      float* __restrict__ out) {
    const int row = blockIdx.x * 256 + threadIdx.x;
    float m0 = FLTMAX, m1 = FLTMAX, m2 = FLTMAX, mx = 0.0f;
    for (int s = 0; s < 64; ++s) {
        float4 t = part4[(size_t)s * NROWS + row];
        float n0 = fminf(m0, t.x);
        float n1 = fminf(fmaxf(m0, t.x), fminf(m1, t.y));
        float n2 = fminf(fminf(m2, t.z), fminf(fmaxf(m0, t.y), fmaxf(m1, t.x)));
        m0 = n0; m1 = n1; m2 = n2; mx = fmaxf(mx, t.w);
    }
    float d1 = sqrtf(fmaxf(m1, 0.0f) + 1e-12f);
    float d2 = sqrtf(fmaxf(m2, 0.0f) + 1e-12f);
    float dm = sqrtf(fmaxf(mx, 0.0f) + 1e-12f);
    out[row] = (d1 / d2 < 0.6f) ? 2.0f / (1.0f + expf(d1))
                                : 2.0f / (1.0f + 2.0f * expf(dm));
}

// ============================================================================
// Path B (fallback, fp32 VALU) if ws too small
// ============================================================================

__global__ __launch_bounds__(256) void sq_kernel(const float* __restrict__ x,
                                                 float* __restrict__ sq) {
    int wid = threadIdx.x >> 6;
    int lane = threadIdx.x & 63;
    int row = blockIdx.x * 4 + wid;
    const float* f = x + (size_t)row * CDIM;
    float4 v0 = *(const float4*)(f + lane * 8);
    float4 v1 = *(const float4*)(f + lane * 8 + 4);
    float s = v0.x*v0.x + v0.y*v0.y + v0.z*v0.z + v0.w*v0.w
            + v1.x*v1.x + v1.y*v1.y + v1.z*v1.z + v1.w*v1.w;
    #pragma unroll
    for (int o = 32; o > 0; o >>= 1) s += __shfl_xor(s, o);
    if (lane == 0) sq[row] = s;
}

__global__ __launch_bounds__(256, 2) void fcm_kernel(const float* __restrict__ x,
                                                     const float* __restrict__ sq,
                                                     float* __restrict__ out) {
    __shared__ __align__(16) float a_s[32][36];
    __shared__ __align__(16) float b_s[32][260];
    const int tid = threadIdx.x;
    const int ty = tid >> 6;
    const int tx = tid & 63;
    const int brow = blockIdx.x * 32;
    const int batch = brow >> 12;
    const int irow = brow & (NPTS - 1);
    const float* f = x + (size_t)batch * NPTS * CDIM;
    const float* sqb = sq + batch * NPTS;

    float srr[8];
    #pragma unroll
    for (int r = 0; r < 8; ++r) srr[r] = sqb[irow + ty * 8 + r];
    float m0[8], m1[8], m2[8], mx[8];
    #pragma unroll
    for (int r = 0; r < 8; ++r) {
        m0[r] = FLTMAX; m1[r] = FLTMAX; m2[r] = FLTMAX; mx[r] = 0.0f;
    }
    for (int ct = 0; ct < NPTS / 256; ++ct) {
        const int cbase = ct * 256;
        float acc[8][4];
        #pragma unroll
        for (int r = 0; r < 8; ++r)
            #pragma unroll
            for (int q = 0; q < 4; ++q) acc[r][q] = 0.0f;
        for (int kc = 0; kc < CDIM; kc += 32) {
            {
                int row = tid >> 3, l8 = tid & 7;
                float4 v = *(const float4*)(f + (size_t)(irow + row) * CDIM + kc + l8 * 4);
                a_s[l8 * 4 + 0][row] = v.x; a_s[l8 * 4 + 1][row] = v.y;
                a_s[l8 * 4 + 2][row] = v.z; a_s[l8 * 4 + 3][row] = v.w;
            }
            {
                int colb = tid >> 2, l4 = tid & 3;
                #pragma unroll
                for (int it = 0; it < 4; ++it) {
                    int col = colb + 64 * it;
                    const float* p = f + (size_t)(cbase + col) * CDIM + kc + l4 * 8;
                    float4 v0 = *(const float4*)p;
                    float4 v1 = *(const float4*)(p + 4);
                    b_s[l4 * 8 + 0][col] = v0.x; b_s[l4 * 8 + 1][col] = v0.y;
                    b_s[l4 * 8 + 2][col] = v0.z; b_s[l4 * 8 + 3][col] = v0.w;
                    b_s[l4 * 8 + 4][col] = v1.x; b_s[l4 * 8 + 5][col] = v1.y;
                    b_s[l4 * 8 + 6][col] = v1.z; b_s[l4 * 8 + 7][col] = v1.w;
                }
            }
            __syncthreads();
            #pragma unroll
            for (int k = 0; k < 32; ++k) {
                float a0[8], b0[4];
                *(float4*)&a0[0] = *(const float4*)&a_s[k][ty * 8];
                *(float4*)&a0[4] = *(const float4*)&a_s[k][ty * 8 + 4];
                *(float4*)&b0[0] = *(const float4*)&b_s[k][tx * 4];
                #pragma unroll
                for (int r = 0; r < 8; ++r)
                    #pragma unroll
                    for (int q = 0; q < 4; ++q)
                        acc[r][q] = fmaf(a0[r], b0[q], acc[r][q]);
            }
            __syncthreads();
        }
        #pragma unroll
        for (int q = 0; q < 4; ++q) {
            float sc = sqb[cbase + tx * 4 + q];
            #pragma unroll
            for (int r = 0; r < 8; ++r) {
                float d2v = fmaf(-2.0f, acc[r][q], srr[r] + sc);
                d2v = fmaxf(d2v, 0.0f);
                float d = sqrtf(d2v + 1e-12f);
                float lo = fminf(m0[r], d), hi = fmaxf(m0[r], d);
                m0[r] = lo;
                float lo1 = fminf(m1[r], hi), hi1 = fmaxf(m1[r], hi);
                m1[r] = lo1;
                m2[r] = fminf(m2[r], hi1);
                mx[r] = fmaxf(mx[r], d);
            }
        }
    }
    #pragma unroll
    for (int s = 1; s < 64; s <<= 1) {
        #pragma unroll
        for (int r = 0; r < 8; ++r) {
            float b0v = __shfl_xor(m0[r], s);
            float b1v = __shfl_xor(m1[r], s);
            float b2v = __shfl_xor(m2[r], s);
            float bmv = __shfl_xor(mx[r], s);
            float n0 = fminf(m0[r], b0v);
            float n1 = fminf(fmaxf(m0[r], b0v), fminf(m1[r], b1v));
            float n2 = fminf(fminf(m2[r], b2v),
                             fminf(fmaxf(m0[r], b1v), fmaxf(m1[r], b0v)));
            m0[r] = n0; m1[r] = n1; m2[r] = n2; mx[r] = fmaxf(mx[r], bmv);
        }
    }
    if (tx == 0) {
        #pragma unroll
        for (int r = 0; r < 8; ++r) {
            int grow = brow + ty * 8 + r;
            float d1 = m1[r], d2nd = m2[r], dmaxv = mx[r];
            float pred = (d1 / d2nd < 0.6f) ? 2.0f / (1.0f + expf(d1))
                                            : 2.0f / (1.0f + 2.0f * expf(dmaxv));
            out[grow] = pred;
        }
    }
}

extern "C" void kernel_launch(void* const* d_in, const int* in_sizes, int n_in,
                              void* d_out, int out_size, void* d_ws, size_t ws_size,
                              hipStream_t stream) {
    const float* x = (const float*)d_in[0];
    float* out = (float*)d_out;

    const size_t plane = (size_t)NROWS * CDIM * sizeof(half_t);      // 16 MB
    const size_t partb = (size_t)64 * NROWS * sizeof(float4);        // 16 MB
    const size_t need = plane + NROWS * sizeof(float) + partb;

    if (ws_size >= need) {
        half_t* hi = (half_t*)d_ws;
        float* sq = (float*)((char*)d_ws + plane);
        float4* part4 = (float4*)((char*)d_ws + plane + NROWS * sizeof(float));
        prep_kernel<<<dim3(NROWS / 4), dim3(256), 0, stream>>>(x, hi, sq);
        fcm_sym<<<dim3(4 * NTILES), dim3(256), 0, stream>>>(hi, sq, part4);
        combine_kernel<<<dim3(NROWS / 256), dim3(256), 0, stream>>>(part4, out);
    } else {
        float* sqw = (float*)d_ws;
        sq_kernel<<<dim3(4096), dim3(256), 0, stream>>>(x, sqw);
        fcm_kernel<<<dim3(512), dim3(256), 0, stream>>>(x, sqw, out);
    }
}

// Round 16
// 73.833 us; speedup vs baseline: 1.0465x; 1.0465x over previous
//
#include <hip/hip_runtime.h>
#include <math.h>

#define NPTS 4096
#define CDIM 512
#define NROWS 16384
#define NTILES 528   // 32*33/2 tri-tiles of 128 per batch
#define FLTMAX 3.402823466e+38f

typedef _Float16 half_t;
typedef _Float16 half8 __attribute__((ext_vector_type(8)));
typedef float f32x4 __attribute__((ext_vector_type(4)));

__device__ inline void gl_lds16(const void* g, void* l) {
    __builtin_amdgcn_global_load_lds(
        (const __attribute__((address_space(1))) uint32_t*)g,
        (__attribute__((address_space(3))) uint32_t*)l, 16, 0, 0);
}

// Super-tile order: per batch, 4x4 super-grid of 8x8 tiles (upper triangle,
// 10 supers). Decode t in [0,528) -> (I,J), J>=I. Keeps each XCD's resident
// tiles L2-compact (verified R10: FETCH 29->18 MB).
__device__ __forceinline__ void super_decode(int t, int& I, int& J) {
    const int cum[10] = {0, 36, 100, 164, 228, 264, 328, 392, 428, 492};
    const int si[10]  = {0, 0, 0, 0, 1, 1, 1, 2, 2, 3};
    const int sj[10]  = {0, 1, 2, 3, 1, 2, 3, 2, 3, 3};
    int s = 0;
    #pragma unroll
    for (int k = 1; k < 10; ++k) s += (t >= cum[k]);
    const int u = t - cum[s];
    int i, j;
    if (si[s] == sj[s]) {
        i = 0;
        #pragma unroll
        for (int k = 1; k < 8; ++k) {
            const int c8 = k * 8 - (k * (k - 1)) / 2;
            i += (u >= c8);
        }
        const int c8i = i * 8 - (i * (i - 1)) / 2;
        j = i + (u - c8i);
    } else {
        i = u >> 3;
        j = u & 7;
    }
    I = si[s] * 8 + i;
    J = sj[s] * 8 + j;
}

// merge two sorted triples + maxes: (n0<=n1<=n2, nx)
#define TRIMERGE(n0, n1, n2, nx, x0, x1, x2, xx, y0, y1, y2, yx) do {          \
        n0 = fminf(x0, y0);                                                    \
        n1 = fminf(fmaxf(x0, y0), fminf(x1, y1));                              \
        n2 = fminf(fminf(x2, y2), fminf(fmaxf(x0, y1), fmaxf(x1, y0)));        \
        nx = fmaxf(xx, yx);                                                    \
    } while (0)

// ============================================================================
// Path A: prep -> fcm_sym (128x128 tri tiles, super-tile XCD-chunked order,
// tree-merge epilogue) -> combine            [R13 configuration: best measured]
// Global f16 image: row stride 1024 B; 8 Kblocks of 64 ch (128 B); 16B slot s
// of each Kblock stored at position s^(row&7) (pre-baked LDS swizzle).
// ============================================================================

__global__ __launch_bounds__(256) void prep_kernel(const float* __restrict__ x,
                                                   half_t* __restrict__ hi,
                                                   float* __restrict__ sq) {
    const int wv = threadIdx.x >> 6, l = threadIdx.x & 63;
    const int row = blockIdx.x * 4 + wv;
    const float* f = x + (size_t)row * CDIM;
    float4 v0 = *(const float4*)(f + l * 8);
    float4 v1 = *(const float4*)(f + l * 8 + 4);
    float xs[8] = {v0.x, v0.y, v0.z, v0.w, v1.x, v1.y, v1.z, v1.w};
    half8 h;
    float s = 0.0f;
    #pragma unroll
    for (int i = 0; i < 8; ++i) {
        float v = xs[i];
        s = fmaf(v, v, s);
        h[i] = (half_t)v;
    }
    #pragma unroll
    for (int o = 32; o > 0; o >>= 1) s += __shfl_xor(s, o);
    const int kb = l >> 3;
    const int pos = (l & 7) ^ (row & 7);
    *(half8*)(hi + (size_t)row * CDIM + kb * 64 + pos * 8) = h;
    if (l == 0) sq[row] = s;
}

// One block per triangular tile (I,J), J>=I, per batch (super-tile XCD-chunked
// order). 128x128 tile, 4 waves (2x2, 64x64 each), BK=64, double-buffered LDS
// via global_load_lds. Epilogue merges are TREE merges with result
// distribution: each round lanes keep the states matching their lane-bit
// (cndmask select), exchange the partner copies (1 shfl), and merge; states
// halve per round; lane t=(l&15) ends with fully-merged state i=t.
// 60 shuffles vs 256 (row-side), 12 vs 32 (col-side); bit-identical results.
// Row-side -> slot 2J+wn; col-side (skip if I==J) -> slot 2I+wm.
// part layout: [slot][row] float4 (m0,m1,m2,max), d^2 domain.
__global__ __launch_bounds__(256, 2) void fcm_sym(const half_t* __restrict__ hi,
                                                  const float* __restrict__ sq,
                                                  float4* __restrict__ part4) {
    __shared__ __align__(16) char smem[2][2][16384];
    const int tid = threadIdx.x, wv = tid >> 6, l = tid & 63;
    const int wm = wv >> 1, wn = wv & 1;
    const int wg = blockIdx.x;
    const int tl = (wg & 7) * 264 + (wg >> 3);        // XCD-chunked, bijective
    const int batch = tl / NTILES;
    const int t = tl - batch * NTILES;
    int I, J;
    super_decode(t, I, J);
    const int r0 = (batch << 12) + I * 128;
    const int c0 = (batch << 12) + J * 128;
    const char* base = (const char*)hi;

    float sr[16];
    #pragma unroll
    for (int mi = 0; mi < 4; ++mi)
        #pragma unroll
        for (int j = 0; j < 4; ++j)
            sr[mi * 4 + j] = sq[r0 + wm * 64 + mi * 16 + (l >> 4) * 4 + j];
    float scn[4];
    #pragma unroll
    for (int ni = 0; ni < 4; ++ni)
        scn[ni] = sq[c0 + wn * 64 + ni * 16 + (l & 15)];

    // fragment byte offsets within A/B LDS buffers (constant per thread)
    int aoff[4][2], boff[4][2];
    #pragma unroll
    for (int q = 0; q < 4; ++q)
        #pragma unroll
        for (int kc = 0; kc < 2; ++kc) {
            int rowa = wm * 64 + q * 16 + (l & 15);
            aoff[q][kc] = rowa * 128 + ((((l >> 4) + kc * 4) ^ (rowa & 7)) * 16);
            int rowb = wn * 64 + q * 16 + (l & 15);
            boff[q][kc] = rowb * 128 + ((((l >> 4) + kc * 4) ^ (rowb & 7)) * 16);
        }

    int srow[4], sin[4];
    #pragma unroll
    for (int i = 0; i < 4; ++i) {
        int dl = i * 4096 + wv * 1024 + l * 16;
        srow[i] = dl >> 7;
        sin[i] = dl & 127;
    }

#define STAGE(buf, ksv) do {                                                   \
        _Pragma("unroll")                                                      \
        for (int i_ = 0; i_ < 4; ++i_) {                                       \
            const int db_ = i_ * 4096 + wv * 1024;                             \
            gl_lds16(base + (size_t)(r0 + srow[i_]) * 1024 + (ksv) * 128 + sin[i_], \
                     &smem[buf][0][db_]);                                      \
            gl_lds16(base + (size_t)(c0 + srow[i_]) * 1024 + (ksv) * 128 + sin[i_], \
                     &smem[buf][1][db_]);                                      \
        } } while (0)

    f32x4 acc[4][4];
    #pragma unroll
    for (int mi = 0; mi < 4; ++mi)
        #pragma unroll
        for (int ni = 0; ni < 4; ++ni)
            #pragma unroll
            for (int j = 0; j < 4; ++j) acc[mi][ni][j] = 0.0f;

    STAGE(0, 0);
    __syncthreads();
    #pragma unroll
    for (int ks = 0; ks < 8; ++ks) {
        const int cur = ks & 1;
        if (ks < 7) STAGE(cur ^ 1, ks + 1);
        #pragma unroll
        for (int kc = 0; kc < 2; ++kc) {
            half8 af[4], bf[4];
            #pragma unroll
            for (int q = 0; q < 4; ++q) {
                af[q] = *(const half8*)&smem[cur][0][aoff[q][kc]];
                bf[q] = *(const half8*)&smem[cur][1][boff[q][kc]];
            }
            #pragma unroll
            for (int mi = 0; mi < 4; ++mi)
                #pragma unroll
                for (int ni = 0; ni < 4; ++ni)
                    acc[mi][ni] = __builtin_amdgcn_mfma_f32_16x16x32_f16(
                        af[mi], bf[ni], acc[mi][ni], 0, 0, 0);
        }
        __syncthreads();
    }
#undef STAGE

    // ---- row-side fold: rows of block I over this tile's 128 cols ----
    float st0[16], st1[16], st2[16], stx[16];
    #pragma unroll
    for (int i = 0; i < 16; ++i) {
        st0[i] = FLTMAX; st1[i] = FLTMAX; st2[i] = FLTMAX; stx[i] = 0.0f;
    }
    #pragma unroll
    for (int ni = 0; ni < 4; ++ni) {
        float sc = scn[ni];
        #pragma unroll
        for (int mi = 0; mi < 4; ++mi)
            #pragma unroll
            for (int j = 0; j < 4; ++j) {
                int idx = mi * 4 + j;
                float d2v = fmaf(-2.0f, acc[mi][ni][j], sr[idx] + sc);
                float lo0 = fminf(st0[idx], d2v), hi0 = fmaxf(st0[idx], d2v);
                st0[idx] = lo0;
                float lo1 = fminf(st1[idx], hi0), hi1 = fmaxf(st1[idx], hi0);
                st1[idx] = lo1;
                st2[idx] = fminf(st2[idx], hi1);
                stx[idx] = fmaxf(stx[idx], d2v);
            }
    }
    // ---- row-side tree-merge: 4 rounds, states 16->8->4->2->1, in place ----
    {
        const int t16 = l & 15;
        #pragma unroll
        for (int rnd = 0; rnd < 4; ++rnd) {
            const int span = 1 << rnd;                 // xor distance
            const int cnt = 8 >> rnd;                  // slots this round
            const bool bit = (t16 & span) != 0;
            #pragma unroll
            for (int q = 0; q < 8; ++q) {
                if (q >= cnt) break;
                float A0 = st0[2 * q],     A1 = st1[2 * q];
                float A2 = st2[2 * q],     AX = stx[2 * q];
                float B0 = st0[2 * q + 1], B1 = st1[2 * q + 1];
                float B2 = st2[2 * q + 1], BX = stx[2 * q + 1];
                float m0v = bit ? B0 : A0, m1v = bit ? B1 : A1;
                float m2v = bit ? B2 : A2, mxv = bit ? BX : AX;
                float o0 = bit ? A0 : B0, o1 = bit ? A1 : B1;
                float o2 = bit ? A2 : B2, ox = bit ? AX : BX;
                float p0 = __shfl_xor(o0, span);
                float p1 = __shfl_xor(o1, span);
                float p2 = __shfl_xor(o2, span);
                float px = __shfl_xor(ox, span);
                TRIMERGE(st0[q], st1[q], st2[q], stx[q],
                         m0v, m1v, m2v, mxv, p0, p1, p2, px);
            }
        }
        // lane t16 now holds merged state i = t16 (mi = t16>>2, j = t16&3)
        const int row = r0 + wm * 64 + (t16 >> 2) * 16 + (l >> 4) * 4 + (t16 & 3);
        part4[(size_t)(2 * J + wn) * NROWS + row] =
            make_float4(st0[0], st1[0], st2[0], stx[0]);
    }

    // ---- col-side fold: rows of block J over this tile's 128 rows ----
    if (J > I) {
        float c0s[4], c1s[4], c2s[4], cxs[4];
        #pragma unroll
        for (int ni = 0; ni < 4; ++ni) {
            c0s[ni] = FLTMAX; c1s[ni] = FLTMAX; c2s[ni] = FLTMAX; cxs[ni] = 0.0f;
        }
        #pragma unroll
        for (int ni = 0; ni < 4; ++ni) {
            float sc = scn[ni];
            #pragma unroll
            for (int mi = 0; mi < 4; ++mi)
                #pragma unroll
                for (int j = 0; j < 4; ++j) {
                    float d2v = fmaf(-2.0f, acc[mi][ni][j], sr[mi * 4 + j] + sc);
                    float lo0 = fminf(c0s[ni], d2v), hi0 = fmaxf(c0s[ni], d2v);
                    c0s[ni] = lo0;
                    float lo1 = fminf(c1s[ni], hi0), hi1 = fmaxf(c1s[ni], hi0);
                    c1s[ni] = lo1;
                    c2s[ni] = fminf(c2s[ni], hi1);
                    cxs[ni] = fmaxf(cxs[ni], d2v);
                }
        }
        // col-side tree-merge: 2 rounds over lane-groups (xor 16, 32)
        {
            #pragma unroll
            for (int rnd = 0; rnd < 2; ++rnd) {
                const int span = 16 << rnd;
                const int cnt = 2 >> rnd;
                const bool bit = (l & span) != 0;
                #pragma unroll
                for (int q = 0; q < 2; ++q) {
                    if (q >= cnt) break;
                    float A0 = c0s[2 * q],     A1 = c1s[2 * q];
                    float A2 = c2s[2 * q],     AX = cxs[2 * q];
                    float B0 = c0s[2 * q + 1], B1 = c1s[2 * q + 1];
                    float B2 = c2s[2 * q + 1], BX = cxs[2 * q + 1];
                    float m0v = bit ? B0 : A0, m1v = bit ? B1 : A1;
                    float m2v = bit ? B2 : A2, mxv = bit ? BX : AX;
                    float o0 = bit ? A0 : B0, o1 = bit ? A1 : B1;
                    float o2 = bit ? A2 : B2, ox = bit ? AX : BX;
                    float p0 = __shfl_xor(o0, span);
                    float p1 = __shfl_xor(o1, span);
                    float p2 = __shfl_xor(o2, span);
                    float px = __shfl_xor(ox, span);
                    TRIMERGE(c0s[q], c1s[q], c2s[q], cxs[q],
                             m0v, m1v, m2v, mxv, p0, p1, p2, px);
                }
            }
            // lane group g = l>>4 holds merged state ni = g
            const int colr = c0 + wn * 64 + ((l >> 4) & 3) * 16 + (l & 15);
            part4[(size_t)(2 * I + wm) * NROWS + colr] =
                make_float4(c0s[0], c1s[0], c2s[0], cxs[0]);
        }
    }
}

// combine: fold all 64 slots per row (each written exactly once), sqrt + pred.
__global__ __launch_bounds__(256) void combine_kernel(const float4* __restrict__ part4,
                                                      float* __restrict__ out) {
    const int row = blockIdx.x * 256 + threadIdx.x;
    float m0 = FLTMAX, m1 = FLTMAX, m2 = FLTMAX, mx = 0.0f;
    for (int s = 0; s < 64; ++s) {
        float4 t = part4[(size_t)s * NROWS + row];
        float n0 = fminf(m0, t.x);
        float n1 = fminf(fmaxf(m0, t.x), fminf(m1, t.y));
        float n2 = fminf(fminf(m2, t.z), fminf(fmaxf(m0, t.y), fmaxf(m1, t.x)));
        m0 = n0; m1 = n1; m2 = n2; mx = fmaxf(mx, t.w);
    }
    float d1 = sqrtf(fmaxf(m1, 0.0f) + 1e-12f);
    float d2 = sqrtf(fmaxf(m2, 0.0f) + 1e-12f);
    float dm = sqrtf(fmaxf(mx, 0.0f) + 1e-12f);
    out[row] = (d1 / d2 < 0.6f) ? 2.0f / (1.0f + expf(d1))
                                : 2.0f / (1.0f + 2.0f * expf(dm));
}

// ============================================================================
// Path B (fallback, fp32 VALU) if ws too small
// ============================================================================

__global__ __launch_bounds__(256) void sq_kernel(const float* __restrict__ x,
                                                 float* __restrict__ sq) {
    int wid = threadIdx.x >> 6;
    int lane = threadIdx.x & 63;
    int row = blockIdx.x * 4 + wid;
    const float* f = x + (size_t)row * CDIM;
    float4 v0 = *(const float4*)(f + lane * 8);
    float4 v1 = *(const float4*)(f + lane * 8 + 4);
    float s = v0.x*v0.x + v0.y*v0.y + v0.z*v0.z + v0.w*v0.w
            + v1.x*v1.x + v1.y*v1.y + v1.z*v1.z + v1.w*v1.w;
    #pragma unroll
    for (int o = 32; o > 0; o >>= 1) s += __shfl_xor(s, o);
    if (lane == 0) sq[row] = s;
}

__global__ __launch_bounds__(256, 2) void fcm_kernel(const float* __restrict__ x,
                                                     const float* __restrict__ sq,
                                                     float* __restrict__ out) {
    __shared__ __align__(16) float a_s[32][36];
    __shared__ __align__(16) float b_s[32][260];
    const int tid = threadIdx.x;
    const int ty = tid >> 6;
    const int tx = tid & 63;
    const int brow = blockIdx.x * 32;
    const int batch = brow >> 12;
    const int irow = brow & (NPTS - 1);
    const float* f = x + (size_t)batch * NPTS * CDIM;
    const float* sqb = sq + batch * NPTS;

    float srr[8];
    #pragma unroll
    for (int r = 0; r < 8; ++r) srr[r] = sqb[irow + ty * 8 + r];
    float m0[8], m1[8], m2[8], mx[8];
    #pragma unroll
    for (int r = 0; r < 8; ++r) {
        m0[r] = FLTMAX; m1[r] = FLTMAX; m2[r] = FLTMAX; mx[r] = 0.0f;
    }
    for (int ct = 0; ct < NPTS / 256; ++ct) {
        const int cbase = ct * 256;
        float acc[8][4];
        #pragma unroll
        for (int r = 0; r < 8; ++r)
            #pragma unroll
            for (int q = 0; q < 4; ++q) acc[r][q] = 0.0f;
        for (int kc = 0; kc < CDIM; kc += 32) {
            {
                int row = tid >> 3, l8 = tid & 7;
                float4 v = *(const float4*)(f + (size_t)(irow + row) * CDIM + kc + l8 * 4);
                a_s[l8 * 4 + 0][row] = v.x; a_s[l8 * 4 + 1][row] = v.y;
                a_s[l8 * 4 + 2][row] = v.z; a_s[l8 * 4 + 3][row] = v.w;
            }
            {
                int colb = tid >> 2, l4 = tid & 3;
                #pragma unroll
                for (int it = 0; it < 4; ++it) {
                    int col = colb + 64 * it;
                    const float* p = f + (size_t)(cbase + col) * CDIM + kc + l4 * 8;
                    float4 v0 = *(const float4*)p;
                    float4 v1 = *(const float4*)(p + 4);
                    b_s[l4 * 8 + 0][col] = v0.x; b_s[l4 * 8 + 1][col] = v0.y;
                    b_s[l4 * 8 + 2][col] = v0.z; b_s[l4 * 8 + 3][col] = v0.w;
                    b_s[l4 * 8 + 4][col] = v1.x; b_s[l4 * 8 + 5][col] = v1.y;
                    b_s[l4 * 8 + 6][col] = v1.z; b_s[l4 * 8 + 7][col] = v1.w;
                }
            }
            __syncthreads();
            #pragma unroll
            for (int k = 0; k < 32; ++k) {
                float a0[8], b0[4];
                *(float4*)&a0[0] = *(const float4*)&a_s[k][ty * 8];
                *(float4*)&a0[4] = *(const float4*)&a_s[k][ty * 8 + 4];
                *(float4*)&b0[0] = *(const float4*)&b_s[k][tx * 4];
                #pragma unroll
                for (int r = 0; r < 8; ++r)
                    #pragma unroll
                    for (int q = 0; q < 4; ++q)
                        acc[r][q] = fmaf(a0[r], b0[q], acc[r][q]);
            }
            __syncthreads();
        }
        #pragma unroll
        for (int q = 0; q < 4; ++q) {
            float sc = sqb[cbase + tx * 4 + q];
            #pragma unroll
            for (int r = 0; r < 8; ++r) {
                float d2v = fmaf(-2.0f, acc[r][q], srr[r] + sc);
                d2v = fmaxf(d2v, 0.0f);
                float d = sqrtf(d2v + 1e-12f);
                float lo = fminf(m0[r], d), hi = fmaxf(m0[r], d);
                m0[r] = lo;
                float lo1 = fminf(m1[r], hi), hi1 = fmaxf(m1[r], hi);
                m1[r] = lo1;
                m2[r] = fminf(m2[r], hi1);
                mx[r] = fmaxf(mx[r], d);
            }
        }
    }
    #pragma unroll
    for (int s = 1; s < 64; s <<= 1) {
        #pragma unroll
        for (int r = 0; r < 8; ++r) {
            float b0v = __shfl_xor(m0[r], s);
            float b1v = __shfl_xor(m1[r], s);
            float b2v = __shfl_xor(m2[r], s);
            float bmv = __shfl_xor(mx[r], s);
            float n0 = fminf(m0[r], b0v);
            float n1 = fminf(fmaxf(m0[r], b0v), fminf(m1[r], b1v));
            float n2 = fminf(fminf(m2[r], b2v),
                             fminf(fmaxf(m0[r], b1v), fmaxf(m1[r], b0v)));
            m0[r] = n0; m1[r] = n1; m2[r] = n2; mx[r] = fmaxf(mx[r], bmv);
        }
    }
    if (tx == 0) {
        #pragma unroll
        for (int r = 0; r < 8; ++r) {
            int grow = brow + ty * 8 + r;
            float d1 = m1[r], d2nd = m2[r], dmaxv = mx[r];
            float pred = (d1 / d2nd < 0.6f) ? 2.0f / (1.0f + expf(d1))
                                            : 2.0f / (1.0f + 2.0f * expf(dmaxv));
            out[grow] = pred;
        }
    }
}

extern "C" void kernel_launch(void* const* d_in, const int* in_sizes, int n_in,
                              void* d_out, int out_size, void* d_ws, size_t ws_size,
                              hipStream_t stream) {
    const float* x = (const float*)d_in[0];
    float* out = (float*)d_out;

    const size_t plane = (size_t)NROWS * CDIM * sizeof(half_t);      // 16 MB
    const size_t partb = (size_t)64 * NROWS * sizeof(float4);        // 16 MB
    const size_t need = plane + NROWS * sizeof(float) + partb;

    if (ws_size >= need) {
        half_t* hi = (half_t*)d_ws;
        float* sq = (float*)((char*)d_ws + plane);
        float4* part4 = (float4*)((char*)d_ws + plane + NROWS * sizeof(float));
        prep_kernel<<<dim3(NROWS / 4), dim3(256), 0, stream>>>(x, hi, sq);
        fcm_sym<<<dim3(4 * NTILES), dim3(256), 0, stream>>>(hi, sq, part4);
        combine_kernel<<<dim3(NROWS / 256), dim3(256), 0, stream>>>(part4, out);
    } else {
        float* sqw = (float*)d_ws;
        sq_kernel<<<dim3(4096), dim3(256), 0, stream>>>(x, sqw);
        fcm_kernel<<<dim3(512), dim3(256), 0, stream>>>(x, sqw, out);
    }
}